// Round 2
// baseline (543.780 us; speedup 1.0000x reference)
//
#include <hip/hip_runtime.h>

// StratifiedRaysampler on MI355X — v4: phase-constant lanes, fill-like loop.
//
// Output: points [262144,128,3] f32 then lengths [262144,128,1] f32 =
// 33,554,432 float4s (512 MiB). Write-BW bound; dirs input is 3 MiB.
//
// v3 (fat grid-stride blocks) moved dur_us only 545->536: either the kernel
// is capped ~2.7 TB/s by per-store baggage (3 vector loads + 2 magic divs +
// IEEE divide + branchy select per ONE 16B store), or it was already
// BW-bound and dur_us is dominated by the harness poison-fill (~340us @
// 6.3 TB/s) + reset overhead. v4 removes ALL per-iteration baggage to
// decide it:
//
//   * 192 float4s == exactly 2 rays. A wave owns whole 192-f4 segments;
//     lane l always serves slots l, l+64, l+128 -> per-slot (j, e, z0, z1)
//     are LOOP-INVARIANT, hoisted to registers (12 z + 12 selector codes).
//   * dirs reads become 6 wave-uniform scalar loads per segment (s_load,
//     zero vector-memory loads in the loop).
//   * 8192 waves x exactly 16 segments each — no tail, no divergence;
//     every store is a full-wave contiguous 1 KiB burst.
//   * lengths value depends only on (gt&31): computed ONCE, then 16 pure
//     stores — literally a fill.
//
// Math is expression-identical to v2/v3 (which passed): rx=dx*(1/dz),
// z0=kMinD+j*kStep, z1=z0+kStep; component patterns by e=f0%3:
//   e0:(z0*rx,z0*ry,z0,z1*rx) e1:(z0*ry,z0,z1*rx,z1*ry) e2:(z0,z1*rx,z1*ry,z1)
// Unified: component c multiplier is cycle[(e+c)%3] of {rx,ry,1}, coeff is
// z1 when e+c>=3 else z0.

constexpr int      kNPts       = 128;
constexpr int      kNRays      = 262144;
constexpr float    kMinD       = 0.1f;
constexpr float    kMaxD       = 6.0f;
constexpr float    kStep       = (kMaxD - kMinD) / (float)(kNPts - 1);
constexpr unsigned kPtsF4      = (unsigned)kNRays * kNPts * 3 / 4; // 25,165,824
constexpr unsigned kLenF4      = (unsigned)kNRays * kNPts / 4;     //  8,388,608
constexpr unsigned kBlocks     = 2048;
constexpr unsigned kThreads    = 256;
constexpr unsigned kTotThreads = kBlocks * kThreads;               // 524,288
constexpr unsigned kWaves      = kTotThreads / 64;                 // 8,192
constexpr unsigned kSegs       = kPtsF4 / 192;                     // 131,072
constexpr unsigned kSegPerWave = kSegs / kWaves;                   // 16 (exact)
constexpr unsigned kLenPerThr  = kLenF4 / kTotThreads;             // 16 (exact)

// Per-lane loop-invariant constants for one slot (f4 index s within a
// 192-f4 / 2-ray segment).  q* in {0,1,2} selects {rx, ry, 1}.
#define SLOT_INIT(N, sidx)                                                   \
  unsigned isB##N; float za##N, zb##N, zc##N, zd##N;                         \
  unsigned qa##N, qb##N, qc##N, qd##N;                                       \
  {                                                                          \
    const unsigned s  = (sidx);                                              \
    isB##N            = (s >= 96u) ? 1u : 0u;                                \
    const unsigned sp = s - (isB##N ? 96u : 0u);                             \
    const unsigned f0 = sp * 4u;                                             \
    const unsigned j  = f0 / 3u;                                             \
    const unsigned e  = f0 - j * 3u;                                         \
    const float z0 = kMinD + (float)j * kStep;                               \
    const float z1 = z0 + kStep;                                             \
    za##N = (e + 0u >= 3u) ? z1 : z0;  qa##N = (e + 0u) % 3u;                \
    zb##N = (e + 1u >= 3u) ? z1 : z0;  qb##N = (e + 1u) % 3u;                \
    zc##N = (e + 2u >= 3u) ? z1 : z0;  qc##N = (e + 2u) % 3u;                \
    zd##N = (e + 3u >= 3u) ? z1 : z0;  qd##N = (e + 3u) % 3u;                \
  }

#define SLOT_STORE(N, off)                                                   \
  do {                                                                       \
    const float rx = isB##N ? rxB : rxA;                                     \
    const float ry = isB##N ? ryB : ryA;                                     \
    float4 v;                                                                \
    v.x = za##N * (qa##N == 0u ? rx : (qa##N == 1u ? ry : 1.0f));            \
    v.y = zb##N * (qb##N == 0u ? rx : (qb##N == 1u ? ry : 1.0f));            \
    v.z = zc##N * (qc##N == 0u ? rx : (qc##N == 1u ? ry : 1.0f));            \
    v.w = zd##N * (qd##N == 0u ? rx : (qd##N == 1u ? ry : 1.0f));            \
    out[ubase + (off)] = v;                                                  \
  } while (0)

__global__ __launch_bounds__(256) void StratifiedRaysampler_kernel(
    const float* __restrict__ dirs,   // [N_RAYS,3]
    float4* __restrict__ out)         // points then lengths, as float4
{
    const unsigned t   = threadIdx.x;
    const unsigned l   = t & 63u;
    const unsigned gt  = blockIdx.x * kThreads + t;
    const unsigned wid = (unsigned)__builtin_amdgcn_readfirstlane((int)(gt >> 6));

    // ---- per-lane slot constants (slots l, l+64, l+128) ----
    SLOT_INIT(0, l);
    SLOT_INIT(1, l + 64u);
    SLOT_INIT(2, l + 128u);

    // ---- phase 1: points — 16 segments (2 rays / 3 KiB each) per wave ----
#pragma unroll 4
    for (unsigned k = 0; k < kSegPerWave; ++k) {
        const unsigned g = wid * kSegPerWave + k;      // wave-uniform
        const float* dp = dirs + 6u * g;               // -> s_load
        const float dzA = dp[2], dzB = dp[5];
        const float invA = 1.0f / dzA;
        const float invB = 1.0f / dzB;
        const float rxA = dp[0] * invA, ryA = dp[1] * invA;
        const float rxB = dp[3] * invB, ryB = dp[4] * invB;
        const unsigned ubase = g * 192u + l;
        SLOT_STORE(0, 0u);
        SLOT_STORE(1, 64u);
        SLOT_STORE(2, 128u);
    }

    // ---- phase 2: lengths — value constant per thread, 16 pure stores ----
    {
        const unsigned kk = (gt & 31u) * 4u;
        const float z0 = kMinD + (float)kk * kStep;
        const float4 v = make_float4(z0, z0 + kStep,
                                     z0 + 2.0f * kStep, z0 + 3.0f * kStep);
        unsigned u = kPtsF4 + gt;
#pragma unroll
        for (unsigned m = 0; m < kLenPerThr; ++m) {
            out[u] = v;
            u += kTotThreads;
        }
    }
}

extern "C" void kernel_launch(void* const* d_in, const int* in_sizes, int n_in,
                              void* d_out, int out_size, void* d_ws, size_t ws_size,
                              hipStream_t stream) {
    // d_in[0] = origins (unused by the reference math), d_in[1] = directions
    const float* dirs = (const float*)d_in[1];
    float4* out = (float4*)d_out;

    StratifiedRaysampler_kernel<<<kBlocks, kThreads, 0, stream>>>(dirs, out);
}